// Round 1
// baseline (491.847 us; speedup 1.0000x reference)
//
#include <hip/hip_runtime.h>
#include <math.h>

// ---------------- constants ----------------
#define NNPOS 2304            // 48*48
#define ROWS  18432           // 8 * 2304

// workspace layout (float offsets)
#define O_Q   0ul             // q_raw [row][64]
#define O_K   1179648ul       // k_raw [row][16]
#define O_V   1474560ul       // v_raw [row][32]
#define O_ST  2064384ul       // scale_q[64] bias_q[64] scale_v[32] bias_v[32] denomInv[128]
#define O_VP  2064704ul       // Vp_T bf16 [256][2304]  (294912 float slots)
#define O_QP  2359616ul       // Qp fp32 [n][b][8][16]
#define O_CE  4718912ul       // cor_embed_ [row][64]
#define O_LC  5898560ul       // lamc [b][16][32]
#define O_CR  5902656ul       // cor_reverse_ [row][128]
#define O_D1  8261952ul       // (cor_reverse - ce) [row][64]

typedef __bf16 bf16x8 __attribute__((ext_vector_type(8)));
typedef float  f32x4  __attribute__((ext_vector_type(4)));

__device__ inline float wred(float v) {
#pragma unroll
  for (int off = 32; off > 0; off >>= 1) v += __shfl_down(v, off, 64);
  return v;
}

// ---------------- kernel 1: q,k,v 1x1 convs ----------------
__global__ void k_qkv(const float* __restrict__ x, const float* __restrict__ Wq,
                      const float* __restrict__ Wk, const float* __restrict__ Wv,
                      float* __restrict__ ws) {
  __shared__ float xs[2][128], xr[2][128];
  const int t = threadIdx.x;
  const int row0 = blockIdx.x * 2;
  for (int i = t; i < 512; i += 256) {
    int which = i >> 7, c = i & 127;
    int rid = row0 + (which & 1);
    int b = rid / NNPOS, n = rid - b * NNPOS;
    if (which < 2) xs[which][c] = x[(size_t)(b * NNPOS + n) * 128 + c];
    else           xr[which - 2][c] = x[(size_t)(((b + 4) & 7) * NNPOS + n) * 128 + c];
  }
  __syncthreads();
  const int rl = t >> 7, ch = t & 127;
  const int rid = row0 + rl;
  float acc = 0.f;
  if (ch < 64) {
    const float* w = Wq + ch * 128;
#pragma unroll 16
    for (int c = 0; c < 128; ++c) acc += xs[rl][c] * w[c];
    ws[O_Q + (size_t)rid * 64 + ch] = acc;
  } else if (ch < 80) {
    const float* w = Wk + (ch - 64) * 128;
#pragma unroll 16
    for (int c = 0; c < 128; ++c) acc += xr[rl][c] * w[c];
    ws[O_K + (size_t)rid * 16 + (ch - 64)] = acc;
  } else if (ch < 112) {
    const float* w = Wv + (ch - 80) * 128;
#pragma unroll 16
    for (int c = 0; c < 128; ++c) acc += xr[rl][c] * w[c];
    ws[O_V + (size_t)rid * 32 + (ch - 80)] = acc;
  }
}

// ---------------- kernel 2: BN stats + softmax denominators ----------------
__global__ void k_stats(const float* __restrict__ gq, const float* __restrict__ bq,
                        const float* __restrict__ gv, const float* __restrict__ bv,
                        float* __restrict__ ws) {
  const int t = threadIdx.x, blk = blockIdx.x;
  const int wave = t >> 6, lane = t & 63;
  __shared__ float r1[4], r2[4];
  if (blk < 96) {
    const bool isq = blk < 64;
    const int ch = isq ? blk : blk - 64;
    const float* src = ws + (isq ? O_Q : O_V);
    const int stride = isq ? 64 : 32;
    float s = 0.f, s2 = 0.f;
    for (int r = t; r < ROWS; r += 256) {
      float v = src[(size_t)r * stride + ch];
      s += v; s2 += v * v;
    }
    s = wred(s); s2 = wred(s2);
    if (lane == 0) { r1[wave] = s; r2[wave] = s2; }
    __syncthreads();
    if (t == 0) {
      float S = r1[0] + r1[1] + r1[2] + r1[3];
      float S2 = r2[0] + r2[1] + r2[2] + r2[3];
      float mu = S / 18432.f;
      float var = S2 / 18432.f - mu * mu;
      float g = isq ? gq[ch] : gv[ch];
      float be = isq ? bq[ch] : bv[ch];
      float sc = g * rsqrtf(var + 1e-5f);
      if (isq) { ws[O_ST + ch] = sc;       ws[O_ST + 64 + ch] = be - mu * sc; }
      else     { ws[O_ST + 128 + ch] = sc; ws[O_ST + 160 + ch] = be - mu * sc; }
    }
  } else {
    const int idx = blk - 96;
    const int b = idx >> 4, kc = idx & 15;
    float s = 0.f;
    for (int m = t; m < NNPOS; m += 256)
      s += __expf(ws[O_K + (size_t)(b * NNPOS + m) * 16 + kc]);
    s = wred(s);
    if (lane == 0) r1[wave] = s;
    __syncthreads();
    if (t == 0) ws[O_ST + 192 + idx] = 1.f / (r1[0] + r1[1] + r1[2] + r1[3]);
  }
}

// ---------------- kernel 3: build Vp_T (bf16), Qp (Q' 8 heads), cor_embed ----------------
__global__ void k_prep(const float* __restrict__ cor, const float* __restrict__ Wce,
                       const float* __restrict__ bce, float* __restrict__ ws) {
  const int t = threadIdx.x;
  const int rl = t >> 5, j = t & 31;
  const int rid = blockIdx.x * 8 + rl;
  const int b = rid / NNPOS, n = rid - b * NNPOS;
  const float* st = ws + O_ST;
  __bf16* vp = (__bf16*)(ws + O_VP);
  float vvn = ws[O_V + (size_t)rid * 32 + j] * st[128 + j] + st[160 + j];
  vp[(size_t)(b * 32 + j) * NNPOS + n] = (__bf16)vvn;
  float c0 = cor[rid * 2], c1 = cor[rid * 2 + 1];
#pragma unroll
  for (int ch = j; ch < 64; ch += 32) {
    float qn = ws[O_Q + (size_t)rid * 64 + ch] * st[ch] + st[64 + ch];
    ws[O_QP + (size_t)(n * 8 + b) * 128 + ch] = qn;
    float ce = c0 * Wce[ch * 2] + c1 * Wce[ch * 2 + 1] + bce[ch];
    ws[O_QP + (size_t)(n * 8 + b) * 128 + 64 + ch] = ce;
    ws[O_CE + (size_t)rid * 64 + ch] = ce;
  }
}

// ---------------- kernel 4: lamc[b][kc][v] ----------------
__global__ void k_lamc(float* __restrict__ ws) {
  const int b = blockIdx.x >> 4, kc = blockIdx.x & 15;
  const int v = threadIdx.x & 31, chunk = threadIdx.x >> 5;
  const float* st = ws + O_ST;
  const float sc = st[128 + v], bi = st[160 + v];
  float acc = 0.f;
  const int mbeg = chunk * 288;
  for (int m = mbeg; m < mbeg + 288; ++m) {
    float ek = __expf(ws[O_K + (size_t)(b * NNPOS + m) * 16 + kc]);
    float vn = ws[O_V + (size_t)(b * NNPOS + m) * 32 + v] * sc + bi;
    acc += ek * vn;
  }
  __shared__ float red[8][32];
  red[chunk][v] = acc;
  __syncthreads();
  if (chunk == 0) {
    float s = 0.f;
#pragma unroll
    for (int q = 0; q < 8; ++q) s += red[q][v];
    ws[O_LC + (size_t)(b * 16 + kc) * 32 + v] = s * st[192 + b * 16 + kc];
  }
}

// ---------------- kernel 5: lamp GEMM (gathered E x Vp) + fused Y epilogue ----------------
// grid (288, 2): 8 n per n-group (128 GEMM rows), col-half = 4 batches (128 cols)
__global__ __launch_bounds__(256, 2) void k_lamp(const float* __restrict__ R,
                                                 float* __restrict__ ws,
                                                 float* __restrict__ out) {
  __shared__ __align__(16) char smem[64 * 132 * 4];   // 33792 B, unioned
  __bf16* As = (__bf16*)smem;                // [128][40]  (stride 80 B)
  __bf16* Bs = (__bf16*)(smem + 10240);      // [128][40]
  float*  Cs = (float*)smem;                 // epilogue [64][132]

  const int t = threadIdx.x;
  const int n0 = blockIdx.x * 8;
  const int chalf = blockIdx.y;
  const int wave = t >> 6, lane = t & 63;
  const int wrow = wave >> 1, wcol = wave & 1;
  const int lr = lane & 15, quad = lane >> 4;

  // A-gather setup: rowA = (n_loc, kc)
  const int rowA = t & 127;
  const int kb = (t >> 7) << 4;              // 0 or 16
  const int nA = n0 + (rowA >> 4);
  const int offA = 4512 - (nA + 47 * (nA / 48));
  const float* Rrow = R + (rowA & 15);

  const __bf16* vp = (const __bf16*)(ws + O_VP);
  const int colbase = chalf * 128;

  f32x4 acc[4][4];
  {
    f32x4 zz = {0.f, 0.f, 0.f, 0.f};
#pragma unroll
    for (int i = 0; i < 4; ++i)
#pragma unroll
      for (int j = 0; j < 4; ++j) acc[i][j] = zz;
  }

  for (int ks = 0; ks < 72; ++ks) {
    const int m0 = ks * 32;
    __syncthreads();
    // stage A (gathered rel-pos emb -> bf16)
    float fv[16];
#pragma unroll
    for (int i = 0; i < 16; ++i) {
      int m = m0 + kb + i;
      int g = m + 47 * (m / 48);
      fv[i] = Rrow[((g + offA) << 4)];
    }
    bf16x8 p0, p1;
#pragma unroll
    for (int i = 0; i < 8; ++i) { p0[i] = (__bf16)fv[i]; p1[i] = (__bf16)fv[8 + i]; }
    *(bf16x8*)(As + rowA * 40 + kb) = p0;
    *(bf16x8*)(As + rowA * 40 + kb + 8) = p1;
    // stage B (Vp_T slices, already bf16)
    for (int c = t; c < 512; c += 256) {
      int col = c >> 2, part = c & 3;
      bf16x8 d = *(const bf16x8*)(vp + (size_t)(colbase + col) * NNPOS + m0 + part * 8);
      *(bf16x8*)(Bs + col * 40 + part * 8) = d;
    }
    __syncthreads();
    // fragments + MFMA
    bf16x8 af[4], bfr[4];
#pragma unroll
    for (int rt = 0; rt < 4; ++rt)
      af[rt] = *(const bf16x8*)(As + (wrow * 64 + rt * 16 + lr) * 40 + quad * 8);
#pragma unroll
    for (int ct = 0; ct < 4; ++ct)
      bfr[ct] = *(const bf16x8*)(Bs + (wcol * 64 + ct * 16 + lr) * 40 + quad * 8);
#pragma unroll
    for (int rt = 0; rt < 4; ++rt)
#pragma unroll
      for (int ct = 0; ct < 4; ++ct)
        acc[rt][ct] = __builtin_amdgcn_mfma_f32_16x16x32_bf16(af[rt], bfr[ct], acc[rt][ct], 0, 0, 0);
  }

  // epilogue: Y[b,h',v,n] = sum_kc Q'[b,h',kc,n] * (lamp + lamc)
  const float* lamc = ws + O_LC;
  const float* Qp = ws + O_QP;
  float* CR = ws + O_CR;
  const int s = t >> 5, vv = t & 31;

  for (int h = 0; h < 2; ++h) {
    __syncthreads();
    if (wrow == h) {
#pragma unroll
      for (int rt = 0; rt < 4; ++rt) {
#pragma unroll
        for (int ct = 0; ct < 4; ++ct) {
          int col = wcol * 64 + ct * 16 + lr;
          int bb = chalf * 4 + (col >> 5);
          int vl = col & 31;
#pragma unroll
          for (int reg = 0; reg < 4; ++reg) {
            int row = rt * 16 + quad * 4 + reg;     // local row in half
            int kc = row & 15;
            Cs[row * 132 + col] = acc[rt][ct][reg] + lamc[(bb * 16 + kc) * 32 + vl];
          }
        }
      }
    }
    __syncthreads();
#pragma unroll
    for (int i = 0; i < 16; ++i) {
      int combo = s * 16 + i;
      int hp = combo & 7, bl = (combo >> 3) & 3, nr = combo >> 5;
      int n = n0 + h * 4 + nr;
      int bb = chalf * 4 + bl;
      const float* qrow = Qp + ((size_t)(n * 8 + bb) * 8 + hp) * 16;
      const float* crow = Cs + (nr * 16) * 132 + bl * 32 + vv;
      float y = 0.f;
#pragma unroll
      for (int kc = 0; kc < 16; ++kc) y += qrow[kc] * crow[kc * 132];
      float* dst = (hp < 4) ? out : CR;
      dst[(size_t)(bb * NNPOS + n) * 128 + (hp & 3) * 32 + vv] = y;
    }
  }
}

// ---------------- kernel 6: D1 = CR @ Wcc^T - ce ----------------
__global__ void k_e1(const float* __restrict__ Wcc, float* __restrict__ ws) {
  __shared__ float wt[128 * 65];   // WccT padded [c][o]
  __shared__ float cr[16][128];
  __shared__ float ce[16][64];
  const int t = threadIdx.x;
  const int r0 = blockIdx.x * 16;
  for (int i = t; i < 8192; i += 256) { int o = i >> 7, c = i & 127; wt[c * 65 + o] = Wcc[i]; }
  for (int i = t; i < 2048; i += 256) cr[i >> 7][i & 127] = ws[O_CR + (size_t)r0 * 128 + i];
  for (int i = t; i < 1024; i += 256) ce[i >> 6][i & 63] = ws[O_CE + (size_t)r0 * 64 + i];
  __syncthreads();
  const int o = t & 63, rg = t >> 6;
  float acc[4];
#pragma unroll
  for (int j = 0; j < 4; ++j) acc[j] = -ce[rg + 4 * j][o];
  for (int c = 0; c < 128; ++c) {
    float w = wt[c * 65 + o];
#pragma unroll
    for (int j = 0; j < 4; ++j) acc[j] += cr[rg + 4 * j][c] * w;
  }
#pragma unroll
  for (int j = 0; j < 4; ++j)
    ws[O_D1 + (size_t)(r0 + rg + 4 * j) * 64 + o] = acc[j];
}

// ---------------- kernel 7: motion = D1 @ Wmp^T + bmp ----------------
__global__ void k_e2(const float* __restrict__ Wmp, const float* __restrict__ bmp,
                     float* __restrict__ ws, float* __restrict__ out) {
  __shared__ float wt[64 * 129];   // WmpT padded [o][o2]
  __shared__ float dd[16][64];
  const int t = threadIdx.x;
  const int r0 = blockIdx.x * 16;
  for (int i = t; i < 8192; i += 256) { int o2 = i >> 6, o = i & 63; wt[o * 129 + o2] = Wmp[i]; }
  for (int i = t; i < 1024; i += 256) dd[i >> 6][i & 63] = ws[O_D1 + (size_t)r0 * 64 + i];
  __syncthreads();
  const int o2 = t & 127, rg = t >> 7;
  float acc[8];
  float bb = bmp[o2];
#pragma unroll
  for (int j = 0; j < 8; ++j) acc[j] = bb;
  for (int o = 0; o < 64; ++o) {
    float w = wt[o * 129 + o2];
#pragma unroll
    for (int j = 0; j < 8; ++j) acc[j] += dd[rg + 2 * j][o] * w;
  }
#pragma unroll
  for (int j = 0; j < 8; ++j)
    out[2359296ul + (size_t)(r0 + rg + 2 * j) * 128 + o2] = acc[j];
}

// ---------------- launcher ----------------
extern "C" void kernel_launch(void* const* d_in, const int* in_sizes, int n_in,
                              void* d_out, int out_size, void* d_ws, size_t ws_size,
                              hipStream_t stream) {
  const float* x   = (const float*)d_in[0];
  const float* cor = (const float*)d_in[1];
  const float* Wq  = (const float*)d_in[2];
  const float* Wk  = (const float*)d_in[3];
  const float* Wv  = (const float*)d_in[4];
  const float* Wce = (const float*)d_in[5];
  const float* bce = (const float*)d_in[6];
  const float* Wcc = (const float*)d_in[7];
  const float* Wmp = (const float*)d_in[8];
  const float* bmp = (const float*)d_in[9];
  const float* gq  = (const float*)d_in[10];
  const float* bq  = (const float*)d_in[11];
  const float* gv  = (const float*)d_in[12];
  const float* bv  = (const float*)d_in[13];
  const float* rel = (const float*)d_in[14];
  float* out = (float*)d_out;
  float* ws  = (float*)d_ws;

  k_qkv <<<9216, 256, 0, stream>>>(x, Wq, Wk, Wv, ws);
  k_stats<<<224, 256, 0, stream>>>(gq, bq, gv, bv, ws);
  k_prep <<<2304, 256, 0, stream>>>(cor, Wce, bce, ws);
  k_lamc <<<128, 256, 0, stream>>>(ws);
  k_lamp <<<dim3(288, 2), 256, 0, stream>>>(rel, ws, out);
  k_e1   <<<1152, 256, 0, stream>>>(Wcc, ws);
  k_e2   <<<1152, 256, 0, stream>>>(Wmp, bmp, ws, out);
}

// Round 2
// 389.439 us; speedup vs baseline: 1.2630x; 1.2630x over previous
//
#include <hip/hip_runtime.h>
#include <math.h>

// ---------------- constants ----------------
#define NNPOS 2304            // 48*48
#define ROWS  18432           // 8 * 2304
#define NK    96              // K-steps: 48 mi-blocks x 2 halves of padded-64

// workspace layout (float offsets)
#define O_Q   0ul             // q_raw [row][64]
#define O_K   1179648ul       // k_raw [row][16]
#define O_V   1474560ul       // v_raw [row][32]
#define O_ST  2064384ul       // scale_q[64] bias_q[64] scale_v[32] bias_v[32] denomInv[128]
#define O_VP  2064704ul       // Vp_g bf16 [256][3072] padded (393216 float slots)
#define O_QP  2457920ul       // Qp fp32 [n][b][8][16]
#define O_CE  4817216ul       // cor_embed_ [row][64]
#define O_LC  5996864ul       // lamc [b][16][32]
#define O_CR  6000960ul       // cor_reverse_ [row][128]
#define O_RT  8360256ul       // R_T bf16 [16][9216]  (73728 float slots)
#define O_WF  8433984ul       // WfT fp32 [c][o2] = (Wmp@Wcc)^T  (16384)
#define O_WG  8450368ul       // Wg fp32 [o2][2] = Wmp@Wce       (256)
#define O_B2  8450624ul       // b2 fp32 [o2] = bmp - Wmp@bce    (128)

typedef __bf16 bf16x8 __attribute__((ext_vector_type(8)));
typedef float  f32x4  __attribute__((ext_vector_type(4)));
typedef unsigned int u32;
typedef u32 u32x4 __attribute__((ext_vector_type(4)));

__device__ inline float wred(float v) {
#pragma unroll
  for (int off = 32; off > 0; off >>= 1) v += __shfl_down(v, off, 64);
  return v;
}

// ---------------- kernel 1: q,k,v 1x1 convs ----------------
__global__ void k_qkv(const float* __restrict__ x, const float* __restrict__ Wq,
                      const float* __restrict__ Wk, const float* __restrict__ Wv,
                      float* __restrict__ ws) {
  __shared__ float xs[2][128], xr[2][128];
  const int t = threadIdx.x;
  const int row0 = blockIdx.x * 2;
  for (int i = t; i < 512; i += 256) {
    int which = i >> 7, c = i & 127;
    int rid = row0 + (which & 1);
    int b = rid / NNPOS, n = rid - b * NNPOS;
    if (which < 2) xs[which][c] = x[(size_t)(b * NNPOS + n) * 128 + c];
    else           xr[which - 2][c] = x[(size_t)(((b + 4) & 7) * NNPOS + n) * 128 + c];
  }
  __syncthreads();
  const int rl = t >> 7, ch = t & 127;
  const int rid = row0 + rl;
  float acc = 0.f;
  if (ch < 64) {
    const float* w = Wq + ch * 128;
#pragma unroll 16
    for (int c = 0; c < 128; ++c) acc += xs[rl][c] * w[c];
    ws[O_Q + (size_t)rid * 64 + ch] = acc;
  } else if (ch < 80) {
    const float* w = Wk + (ch - 64) * 128;
#pragma unroll 16
    for (int c = 0; c < 128; ++c) acc += xr[rl][c] * w[c];
    ws[O_K + (size_t)rid * 16 + (ch - 64)] = acc;
  } else if (ch < 112) {
    const float* w = Wv + (ch - 80) * 128;
#pragma unroll 16
    for (int c = 0; c < 128; ++c) acc += xr[rl][c] * w[c];
    ws[O_V + (size_t)rid * 32 + (ch - 80)] = acc;
  }
}

// ---------------- kernel: transpose rel_pos_emb -> R_T bf16 [16][96*96] ----------------
__global__ void k_rt(const float* __restrict__ rel, float* __restrict__ ws) {
  __bf16* rt = (__bf16*)(ws + O_RT);
  int i = blockIdx.x * 256 + threadIdx.x;
  if (i < 144400) {                     // 95*95*16
    int kc = i & 15, rr = i >> 4;       // rr < 9025
    int ri = rr / 95, rj = rr - ri * 95;
    rt[(size_t)kc * 9216 + ri * 96 + rj] = (__bf16)rel[i];
  }
}

// ---------------- kernel: fold motion weights ----------------
// WfT[c][o2] = sum_o Wmp[o2][o]*Wcc[o][c];  Wg[o2][j] = sum_o Wmp[o2][o]*Wce[o][j]
// b2[o2] = bmp[o2] - sum_o Wmp[o2][o]*bce[o]
__global__ void k_fold(const float* __restrict__ Wcc, const float* __restrict__ Wce,
                       const float* __restrict__ Wmp, const float* __restrict__ bmp,
                       const float* __restrict__ bce, float* __restrict__ ws) {
  const int t = threadIdx.x;
  const int g = blockIdx.x * 256 + t;
  const int o2 = g >> 7, c = g & 127;
  float acc = 0.f;
#pragma unroll 8
  for (int o = 0; o < 64; ++o) acc += Wmp[o2 * 64 + o] * Wcc[o * 128 + c];
  ws[O_WF + (size_t)c * 128 + o2] = acc;
  if (blockIdx.x == 0 && t < 128) {
    float a0 = 0.f, a1 = 0.f, ab = 0.f;
#pragma unroll 8
    for (int o = 0; o < 64; ++o) {
      float w = Wmp[t * 64 + o];
      a0 += w * Wce[o * 2]; a1 += w * Wce[o * 2 + 1]; ab += w * bce[o];
    }
    ws[O_WG + t * 2] = a0; ws[O_WG + t * 2 + 1] = a1; ws[O_B2 + t] = bmp[t] - ab;
  }
}

// ---------------- kernel: zero the mj>=48 pad of Vp_g ----------------
__global__ void k_zero(float* __restrict__ ws) {
  __bf16* vp = (__bf16*)(ws + O_VP);
  int i = blockIdx.x * 256 + threadIdx.x;   // < 24576 = 256*48*2
  int bv = i / 96, rem = i - bv * 96;
  int mi = rem >> 1, h8 = rem & 1;
  uint4 z; z.x = 0; z.y = 0; z.z = 0; z.w = 0;
  *(uint4*)(vp + (size_t)bv * 3072 + mi * 64 + 48 + h8 * 8) = z;
}

// ---------------- kernel 2: BN stats + softmax denominators ----------------
__global__ void k_stats(const float* __restrict__ gq, const float* __restrict__ bq,
                        const float* __restrict__ gv, const float* __restrict__ bv,
                        float* __restrict__ ws) {
  const int t = threadIdx.x, blk = blockIdx.x;
  const int wave = t >> 6, lane = t & 63;
  __shared__ float r1[4], r2[4];
  if (blk < 96) {
    const bool isq = blk < 64;
    const int ch = isq ? blk : blk - 64;
    const float* src = ws + (isq ? O_Q : O_V);
    const int stride = isq ? 64 : 32;
    float s = 0.f, s2 = 0.f;
    for (int r = t; r < ROWS; r += 256) {
      float v = src[(size_t)r * stride + ch];
      s += v; s2 += v * v;
    }
    s = wred(s); s2 = wred(s2);
    if (lane == 0) { r1[wave] = s; r2[wave] = s2; }
    __syncthreads();
    if (t == 0) {
      float S = r1[0] + r1[1] + r1[2] + r1[3];
      float S2 = r2[0] + r2[1] + r2[2] + r2[3];
      float mu = S / 18432.f;
      float var = S2 / 18432.f - mu * mu;
      float g = isq ? gq[ch] : gv[ch];
      float be = isq ? bq[ch] : bv[ch];
      float sc = g * rsqrtf(var + 1e-5f);
      if (isq) { ws[O_ST + ch] = sc;       ws[O_ST + 64 + ch] = be - mu * sc; }
      else     { ws[O_ST + 128 + ch] = sc; ws[O_ST + 160 + ch] = be - mu * sc; }
    }
  } else {
    const int idx = blk - 96;
    const int b = idx >> 4, kc = idx & 15;
    float s = 0.f;
    for (int m = t; m < NNPOS; m += 256)
      s += __expf(ws[O_K + (size_t)(b * NNPOS + m) * 16 + kc]);
    s = wred(s);
    if (lane == 0) r1[wave] = s;
    __syncthreads();
    if (t == 0) ws[O_ST + 192 + idx] = 1.f / (r1[0] + r1[1] + r1[2] + r1[3]);
  }
}

// ---------------- kernel 3: build Vp_g (bf16, padded), Qp, cor_embed ----------------
__global__ void k_prep(const float* __restrict__ cor, const float* __restrict__ Wce,
                       const float* __restrict__ bce, float* __restrict__ ws) {
  const int t = threadIdx.x;
  const int rl = t >> 5, j = t & 31;
  const int rid = blockIdx.x * 8 + rl;
  const int b = rid / NNPOS, n = rid - b * NNPOS;
  const float* st = ws + O_ST;
  __bf16* vp = (__bf16*)(ws + O_VP);
  float vvn = ws[O_V + (size_t)rid * 32 + j] * st[128 + j] + st[160 + j];
  vp[(size_t)(b * 32 + j) * 3072 + (n / 48) * 64 + (n % 48)] = (__bf16)vvn;
  float c0 = cor[rid * 2], c1 = cor[rid * 2 + 1];
#pragma unroll
  for (int ch = j; ch < 64; ch += 32) {
    float qn = ws[O_Q + (size_t)rid * 64 + ch] * st[ch] + st[64 + ch];
    ws[O_QP + (size_t)(n * 8 + b) * 128 + ch] = qn;
    float ce = c0 * Wce[ch * 2] + c1 * Wce[ch * 2 + 1] + bce[ch];
    ws[O_QP + (size_t)(n * 8 + b) * 128 + 64 + ch] = ce;
    ws[O_CE + (size_t)rid * 64 + ch] = ce;
  }
}

// ---------------- kernel 4: lamc[b][kc][v] ----------------
__global__ void k_lamc(float* __restrict__ ws) {
  const int b = blockIdx.x >> 4, kc = blockIdx.x & 15;
  const int v = threadIdx.x & 31, chunk = threadIdx.x >> 5;
  const float* st = ws + O_ST;
  const float sc = st[128 + v], bi = st[160 + v];
  float acc = 0.f;
  const int mbeg = chunk * 288;
  for (int m = mbeg; m < mbeg + 288; ++m) {
    float ek = __expf(ws[O_K + (size_t)(b * NNPOS + m) * 16 + kc]);
    float vn = ws[O_V + (size_t)(b * NNPOS + m) * 32 + v] * sc + bi;
    acc += ek * vn;
  }
  __shared__ float red[8][32];
  red[chunk][v] = acc;
  __syncthreads();
  if (chunk == 0) {
    float s = 0.f;
#pragma unroll
    for (int q = 0; q < 8; ++q) s += red[q][v];
    ws[O_LC + (size_t)(b * 16 + kc) * 32 + v] = s * st[192 + b * 16 + kc];
  }
}

// ---------------- kernel 5: lamp GEMM + fused Y epilogue (v2) ----------------
// Block: ni in [0,48) x s-set (stride-2 nj octet) x col-half.
// A rows = (nl,kc) 128; n(nl) = ni*48 + s0 + 2*nl  => all frag offsets even.
// K padded: mj in [0,64) per mi-block; Vp_g zeros at mj>=48.
__global__ __launch_bounds__(256, 2) void k_lamp(float* __restrict__ ws,
                                                 float* __restrict__ out) {
  __shared__ __align__(16) char smem[33792];
  bf16x8* Bs16 = (bf16x8*)smem;                  // 512 x 16B units (8 KB)
  u32* Sw = (u32*)(smem + 8192);                 // S[16][50] bf16 = 400 words
  float* Cs = (float*)smem;                      // epilogue [64][132]

  const int t = threadIdx.x;
  const int bx = blockIdx.x;
  const int ni = bx / 6;
  const int sset = bx - ni * 6;
  const int s0 = (sset < 3) ? sset * 16 : (sset - 3) * 16 + 1;
  const int chalf = blockIdx.y;
  const int colbase = chalf * 128;
  const int wave = t >> 6, lane = t & 63;
  const int wrow = wave >> 1, wcol = wave & 1;
  const int lr = lane & 15, quad = lane >> 4;

  const __bf16* vp = (const __bf16*)(ws + O_VP);
  const unsigned short* rp = (const unsigned short*)(ws + O_RT);

  // A-stage: 384 b32-units (16 kc x 24 word-pairs), S row stride 50 elems (25 words)
  const int ia0 = t;
  const int kcA0 = ia0 / 24, wpA0 = ia0 - kcA0 * 24;
  const int ia1 = t + 256;
  const int kcA1 = ia1 / 24, wpA1 = ia1 - kcA1 * 24;
  const bool hasA1 = (ia1 < 384);

  // B-stage: 512 16B-units, swizzled: unit(col,p) = col*4 + ((p + (col>>1))&3)
  const int colB0 = t >> 2, pB0 = ((t & 3) - ((t >> 3) & 3)) & 3;
  const int ub1 = t + 256;
  const int colB1 = ub1 >> 2, pB1 = ((ub1 & 3) - ((ub1 >> 3) & 3)) & 3;
  const __bf16* gB0 = vp + (size_t)(colbase + colB0) * 3072 + pB0 * 8;
  const __bf16* gB1 = vp + (size_t)(colbase + colB1) * 3072 + pB1 * 8;

  f32x4 acc[4][4];
  {
    f32x4 zz = {0.f, 0.f, 0.f, 0.f};
#pragma unroll
    for (int i = 0; i < 4; ++i)
#pragma unroll
      for (int j = 0; j < 4; ++j) acc[i][j] = zz;
  }

  u32 sa0 = 0, sa1 = 0;
  bf16x8 vb0, vb1;

  // prefetch ks = 0  (mi=0, mj0=0, k0=0)
  {
    const int P0 = 96 * (47 - ni) - s0 + 33;
    long b0 = (long)kcA0 * 9216 + P0 + 2 * wpA0;
    if (P0 & 1) sa0 = (u32)rp[b0] | ((u32)rp[b0 + 1] << 16);
    else        sa0 = *(const u32*)(rp + b0);
    if (hasA1) {
      long b1 = (long)kcA1 * 9216 + P0 + 2 * wpA1;
      if (P0 & 1) sa1 = (u32)rp[b1] | ((u32)rp[b1 + 1] << 16);
      else        sa1 = *(const u32*)(rp + b1);
    }
    vb0 = *(const bf16x8*)(gB0);
    vb1 = *(const bf16x8*)(gB1);
  }

  for (int ks = 0; ks < NK; ++ks) {
    __syncthreads();
    Sw[kcA0 * 25 + wpA0] = sa0;
    if (hasA1) Sw[kcA1 * 25 + wpA1] = sa1;
    Bs16[t] = vb0;
    Bs16[t + 256] = vb1;
    __syncthreads();

    if (ks < NK - 1) {
      const int ksn = ks + 1;
      const int mi = ksn >> 1, mj0 = (ksn & 1) << 5;
      const int P0 = 96 * (mi - ni + 47) + mj0 - s0 + 33;
      const int k0 = ksn * 32;
      long b0 = (long)kcA0 * 9216 + P0 + 2 * wpA0;
      if (P0 & 1) sa0 = (u32)rp[b0] | ((u32)rp[b0 + 1] << 16);
      else        sa0 = *(const u32*)(rp + b0);
      if (hasA1) {
        long b1 = (long)kcA1 * 9216 + P0 + 2 * wpA1;
        if (P0 & 1) sa1 = (u32)rp[b1] | ((u32)rp[b1 + 1] << 16);
        else        sa1 = *(const u32*)(rp + b1);
      }
      vb0 = *(const bf16x8*)(gB0 + k0);
      vb1 = *(const bf16x8*)(gB1 + k0);
    }

    bf16x8 af[4], bfr[4];
#pragma unroll
    for (int rt = 0; rt < 4; ++rt) {
      int nl = wrow * 4 + rt;
      int wb = lr * 25 + (7 - nl) + quad * 4;
      u32x4 dd = { Sw[wb], Sw[wb + 1], Sw[wb + 2], Sw[wb + 3] };
      af[rt] = __builtin_bit_cast(bf16x8, dd);
    }
#pragma unroll
    for (int ct = 0; ct < 4; ++ct) {
      int col = wcol * 64 + ct * 16 + lr;
      int u = col * 4 + ((quad + (col >> 1)) & 3);
      bfr[ct] = Bs16[u];
    }
#pragma unroll
    for (int rt = 0; rt < 4; ++rt)
#pragma unroll
      for (int ct = 0; ct < 4; ++ct)
        acc[rt][ct] = __builtin_amdgcn_mfma_f32_16x16x32_bf16(af[rt], bfr[ct], acc[rt][ct], 0, 0, 0);
  }

  // epilogue: Y[b,h',v,n] = sum_kc Q'[b,h',kc,n] * (lamp + lamc)
  const float* lamc = ws + O_LC;
  const float* Qp = ws + O_QP;
  float* CR = ws + O_CR;
  const int s = t >> 5, vv = t & 31;

  for (int h = 0; h < 2; ++h) {
    __syncthreads();
    if (wrow == h) {
#pragma unroll
      for (int rt = 0; rt < 4; ++rt) {
#pragma unroll
        for (int ct = 0; ct < 4; ++ct) {
          int col = wcol * 64 + ct * 16 + lr;
          int bb = chalf * 4 + (col >> 5);
          int vl = col & 31;
#pragma unroll
          for (int reg = 0; reg < 4; ++reg) {
            int row = rt * 16 + quad * 4 + reg;     // local row in half
            int kc = row & 15;
            Cs[row * 132 + col] = acc[rt][ct][reg] + lamc[(bb * 16 + kc) * 32 + vl];
          }
        }
      }
    }
    __syncthreads();
#pragma unroll
    for (int i = 0; i < 16; ++i) {
      int combo = s * 16 + i;
      int hp = combo & 7, bl = (combo >> 3) & 3, nr = combo >> 5;
      int n = ni * 48 + s0 + 2 * (h * 4 + nr);
      int bb = chalf * 4 + bl;
      const float* qrow = Qp + ((size_t)(n * 8 + bb) * 8 + hp) * 16;
      const float* crow = Cs + (nr * 16) * 132 + bl * 32 + vv;
      float y = 0.f;
#pragma unroll
      for (int kc = 0; kc < 16; ++kc) y += qrow[kc] * crow[kc * 132];
      float* dst = (hp < 4) ? out : CR;
      dst[(size_t)(bb * NNPOS + n) * 128 + (hp & 3) * 32 + vv] = y;
    }
  }
}

// ---------------- kernel: motion = CR @ WfT - cor @ Wg^T + b2 ----------------
__global__ void k_motion(const float* __restrict__ cor, float* __restrict__ ws,
                         float* __restrict__ out) {
  __shared__ float cr[16][128];
  __shared__ float cc[16][2];
  const int t = threadIdx.x;
  const int r0 = blockIdx.x * 16;
  for (int i = t; i < 2048; i += 256) cr[i >> 7][i & 127] = ws[O_CR + (size_t)r0 * 128 + i];
  if (t < 32) cc[t >> 1][t & 1] = cor[r0 * 2 + t];
  __syncthreads();
  const int o2 = t & 127, rg = t >> 7;
  const float* wft = ws + O_WF;
  float wg0 = ws[O_WG + o2 * 2], wg1 = ws[O_WG + o2 * 2 + 1], b2 = ws[O_B2 + o2];
  float acc[8];
#pragma unroll
  for (int j = 0; j < 8; ++j) {
    int row = rg + 2 * j;
    acc[j] = b2 - cc[row][0] * wg0 - cc[row][1] * wg1;
  }
  for (int c = 0; c < 128; ++c) {
    float w = wft[c * 128 + o2];
#pragma unroll
    for (int j = 0; j < 8; ++j) acc[j] += cr[rg + 2 * j][c] * w;
  }
#pragma unroll
  for (int j = 0; j < 8; ++j)
    out[2359296ul + (size_t)(r0 + rg + 2 * j) * 128 + o2] = acc[j];
}

// ---------------- launcher ----------------
extern "C" void kernel_launch(void* const* d_in, const int* in_sizes, int n_in,
                              void* d_out, int out_size, void* d_ws, size_t ws_size,
                              hipStream_t stream) {
  const float* x   = (const float*)d_in[0];
  const float* cor = (const float*)d_in[1];
  const float* Wq  = (const float*)d_in[2];
  const float* Wk  = (const float*)d_in[3];
  const float* Wv  = (const float*)d_in[4];
  const float* Wce = (const float*)d_in[5];
  const float* bce = (const float*)d_in[6];
  const float* Wcc = (const float*)d_in[7];
  const float* Wmp = (const float*)d_in[8];
  const float* bmp = (const float*)d_in[9];
  const float* gq  = (const float*)d_in[10];
  const float* bq  = (const float*)d_in[11];
  const float* gv  = (const float*)d_in[12];
  const float* bv  = (const float*)d_in[13];
  const float* rel = (const float*)d_in[14];
  float* out = (float*)d_out;
  float* ws  = (float*)d_ws;

  k_qkv   <<<9216, 256, 0, stream>>>(x, Wq, Wk, Wv, ws);
  k_rt    <<<565, 256, 0, stream>>>(rel, ws);
  k_fold  <<<64, 256, 0, stream>>>(Wcc, Wce, Wmp, bmp, bce, ws);
  k_zero  <<<96, 256, 0, stream>>>(ws);
  k_stats <<<224, 256, 0, stream>>>(gq, bq, gv, bv, ws);
  k_prep  <<<2304, 256, 0, stream>>>(cor, Wce, bce, ws);
  k_lamc  <<<128, 256, 0, stream>>>(ws);
  k_lamp  <<<dim3(288, 2), 256, 0, stream>>>(ws, out);
  k_motion<<<1152, 256, 0, stream>>>(cor, ws, out);
}

// Round 3
// 267.673 us; speedup vs baseline: 1.8375x; 1.4549x over previous
//
#include <hip/hip_runtime.h>
#include <math.h>

// ---------------- constants ----------------
#define NNPOS 2304            // 48*48
#define ROWS  18432           // 8 * 2304
#define NK    96              // K-steps: 48 mi-blocks x 2 halves of padded-64

// workspace layout (float offsets)
#define O_Q   0ul             // q_raw [row][64]
#define O_K   1179648ul       // k_raw [row][16]
#define O_V   1474560ul       // v_raw [row][32]
#define O_ST  2064384ul       // scale_q[64] bias_q[64] scale_v[32] bias_v[32] denomInv[128]
#define O_VP  2064704ul       // Vp_g bf16 [256][3072] padded (393216 float slots)
#define O_QP  2457920ul       // Qp fp32 [n][b][8][16]
#define O_CE  4817216ul       // cor_embed_ [row][64]
#define O_LC  5996864ul       // lamc [b][16][32]
#define O_CR  6000960ul       // cor_reverse_ [row][128]
#define O_RT  8360256ul       // R_T bf16 [16][9216]  (73728 float slots)
#define O_WF  8433984ul       // WfT fp32 [c][o2] = (Wmp@Wcc)^T  (16384)
#define O_WG  8450368ul       // Wg fp32 [o2][2] = Wmp@Wce       (256)
#define O_B2  8450624ul       // b2 fp32 [o2] = bmp - Wmp@bce    (128)
#define O_WB  8450752ul       // Wb bf16 [112][128]  (7168 float slots)

typedef __bf16 bf16x8 __attribute__((ext_vector_type(8)));
typedef float  f32x4  __attribute__((ext_vector_type(4)));
typedef unsigned int u32;
typedef u32 u32x4 __attribute__((ext_vector_type(4)));

__device__ inline float wred(float v) {
#pragma unroll
  for (int off = 32; off > 0; off >>= 1) v += __shfl_down(v, off, 64);
  return v;
}

// ---------------- kernel: fold motion weights + convert qkv weights to bf16 ----------------
__global__ void k_fold(const float* __restrict__ Wcc, const float* __restrict__ Wce,
                       const float* __restrict__ Wmp, const float* __restrict__ bmp,
                       const float* __restrict__ bce, const float* __restrict__ Wq,
                       const float* __restrict__ Wk, const float* __restrict__ Wv,
                       float* __restrict__ ws) {
  const int t = threadIdx.x;
  const int g = blockIdx.x * 256 + t;
  const int o2 = g >> 7, c = g & 127;
  float acc = 0.f;
#pragma unroll 8
  for (int o = 0; o < 64; ++o) acc += Wmp[o2 * 64 + o] * Wcc[o * 128 + c];
  ws[O_WF + (size_t)c * 128 + o2] = acc;
  if (blockIdx.x == 0 && t < 128) {
    float a0 = 0.f, a1 = 0.f, ab = 0.f;
#pragma unroll 8
    for (int o = 0; o < 64; ++o) {
      float w = Wmp[t * 64 + o];
      a0 += w * Wce[o * 2]; a1 += w * Wce[o * 2 + 1]; ab += w * bce[o];
    }
    ws[O_WG + t * 2] = a0; ws[O_WG + t * 2 + 1] = a1; ws[O_B2 + t] = bmp[t] - ab;
  }
  // Wb bf16 [112][128] = concat(Wq, Wk, Wv)
  __bf16* wbp = (__bf16*)(ws + O_WB);
  if (g < 14336) {
    float w;
    if (g < 8192) w = Wq[g];
    else if (g < 10240) w = Wk[g - 8192];
    else w = Wv[g - 10240];
    wbp[g] = (__bf16)w;
  }
}

// ---------------- kernel 1: q,k,v via MFMA  (A = x rows, B = Wb) ----------------
// wave computes 16 rows x 112 cols; block = 64 rows; grid 288.
// q written at row rid; k/v written at batch-rotated row (x_rev fold).
__global__ __launch_bounds__(256) void k_qkv(const float* __restrict__ x,
                                             float* __restrict__ ws) {
  const int t = threadIdx.x;
  const int wave = t >> 6, lane = t & 63;
  const int lr = lane & 15, quad = lane >> 4;
  const int r0 = blockIdx.x * 64 + wave * 16;
  const int b = r0 / NNPOS;
  const int n0 = r0 - b * NNPOS;
  const size_t outbase = (size_t)(((b + 4) & 7)) * NNPOS + n0;   // rotated k/v base

  const __bf16* wb = (const __bf16*)(ws + O_WB);
  const float* xrow = x + (size_t)(r0 + lr) * 128;

  f32x4 acc[7];
#pragma unroll
  for (int i = 0; i < 7; ++i) acc[i] = (f32x4){0.f, 0.f, 0.f, 0.f};

#pragma unroll
  for (int ks = 0; ks < 4; ++ks) {
    const float* ap = xrow + ks * 32 + quad * 8;
    float4 a0 = *(const float4*)(ap);
    float4 a1 = *(const float4*)(ap + 4);
    bf16x8 af;
    af[0] = (__bf16)a0.x; af[1] = (__bf16)a0.y; af[2] = (__bf16)a0.z; af[3] = (__bf16)a0.w;
    af[4] = (__bf16)a1.x; af[5] = (__bf16)a1.y; af[6] = (__bf16)a1.z; af[7] = (__bf16)a1.w;
#pragma unroll
    for (int ct = 0; ct < 7; ++ct) {
      bf16x8 bfrag = *(const bf16x8*)(wb + (ct * 16 + lr) * 128 + ks * 32 + quad * 8);
      acc[ct] = __builtin_amdgcn_mfma_f32_16x16x32_bf16(af, bfrag, acc[ct], 0, 0, 0);
    }
  }

#pragma unroll
  for (int ct = 0; ct < 7; ++ct) {
#pragma unroll
    for (int reg = 0; reg < 4; ++reg) {
      int m = quad * 4 + reg;
      int oc = ct * 16 + lr;
      float vvv = acc[ct][reg];
      if (ct < 4)      ws[O_Q + (size_t)(r0 + m) * 64 + oc] = vvv;
      else if (ct < 5) ws[O_K + (outbase + m) * 16 + (oc - 64)] = vvv;
      else             ws[O_V + (outbase + m) * 32 + (oc - 80)] = vvv;
    }
  }
}

// ---------------- kernel: transpose rel_pos_emb -> R_T bf16 [16][96*96] ----------------
__global__ void k_rt(const float* __restrict__ rel, float* __restrict__ ws) {
  __bf16* rt = (__bf16*)(ws + O_RT);
  int i = blockIdx.x * 256 + threadIdx.x;
  if (i < 144400) {                     // 95*95*16
    int kc = i & 15, rr = i >> 4;       // rr < 9025
    int ri = rr / 95, rj = rr - ri * 95;
    rt[(size_t)kc * 9216 + ri * 96 + rj] = (__bf16)rel[i];
  }
}

// ---------------- kernel: zero the mj>=48 pad of Vp_g ----------------
__global__ void k_zero(float* __restrict__ ws) {
  __bf16* vp = (__bf16*)(ws + O_VP);
  int i = blockIdx.x * 256 + threadIdx.x;   // < 24576 = 256*48*2
  int bv = i / 96, rem = i - bv * 96;
  int mi = rem >> 1, h8 = rem & 1;
  uint4 z; z.x = 0; z.y = 0; z.z = 0; z.w = 0;
  *(uint4*)(vp + (size_t)bv * 3072 + mi * 64 + 48 + h8 * 8) = z;
}

// ---------------- kernel 2: BN stats + softmax denominators ----------------
__global__ void k_stats(const float* __restrict__ gq, const float* __restrict__ bq,
                        const float* __restrict__ gv, const float* __restrict__ bv,
                        float* __restrict__ ws) {
  const int t = threadIdx.x, blk = blockIdx.x;
  const int wave = t >> 6, lane = t & 63;
  __shared__ float r1[4], r2[4];
  if (blk < 96) {
    const bool isq = blk < 64;
    const int ch = isq ? blk : blk - 64;
    const float* src = ws + (isq ? O_Q : O_V);
    const int stride = isq ? 64 : 32;
    float s = 0.f, s2 = 0.f;
    for (int r = t; r < ROWS; r += 256) {
      float v = src[(size_t)r * stride + ch];
      s += v; s2 += v * v;
    }
    s = wred(s); s2 = wred(s2);
    if (lane == 0) { r1[wave] = s; r2[wave] = s2; }
    __syncthreads();
    if (t == 0) {
      float S = r1[0] + r1[1] + r1[2] + r1[3];
      float S2 = r2[0] + r2[1] + r2[2] + r2[3];
      float mu = S / 18432.f;
      float var = S2 / 18432.f - mu * mu;
      float g = isq ? gq[ch] : gv[ch];
      float be = isq ? bq[ch] : bv[ch];
      float sc = g * rsqrtf(var + 1e-5f);
      if (isq) { ws[O_ST + ch] = sc;       ws[O_ST + 64 + ch] = be - mu * sc; }
      else     { ws[O_ST + 128 + ch] = sc; ws[O_ST + 160 + ch] = be - mu * sc; }
    }
  } else {
    const int idx = blk - 96;
    const int b = idx >> 4, kc = idx & 15;
    float s = 0.f;
    for (int m = t; m < NNPOS; m += 256)
      s += __expf(ws[O_K + (size_t)(b * NNPOS + m) * 16 + kc]);
    s = wred(s);
    if (lane == 0) r1[wave] = s;
    __syncthreads();
    if (t == 0) ws[O_ST + 192 + idx] = 1.f / (r1[0] + r1[1] + r1[2] + r1[3]);
  }
}

// ---------------- kernel 3: build Vp_g (bf16, padded), Qp, cor_embed ----------------
__global__ void k_prep(const float* __restrict__ cor, const float* __restrict__ Wce,
                       const float* __restrict__ bce, float* __restrict__ ws) {
  const int t = threadIdx.x;
  const int rl = t >> 5, j = t & 31;
  const int rid = blockIdx.x * 8 + rl;
  const int b = rid / NNPOS, n = rid - b * NNPOS;
  const float* st = ws + O_ST;
  __bf16* vp = (__bf16*)(ws + O_VP);
  float vvn = ws[O_V + (size_t)rid * 32 + j] * st[128 + j] + st[160 + j];
  vp[(size_t)(b * 32 + j) * 3072 + (n / 48) * 64 + (n % 48)] = (__bf16)vvn;
  float c0 = cor[rid * 2], c1 = cor[rid * 2 + 1];
#pragma unroll
  for (int ch = j; ch < 64; ch += 32) {
    float qn = ws[O_Q + (size_t)rid * 64 + ch] * st[ch] + st[64 + ch];
    ws[O_QP + (size_t)(n * 8 + b) * 128 + ch] = qn;
    float ce = c0 * Wce[ch * 2] + c1 * Wce[ch * 2 + 1] + bce[ch];
    ws[O_QP + (size_t)(n * 8 + b) * 128 + 64 + ch] = ce;
    ws[O_CE + (size_t)rid * 64 + ch] = ce;
  }
}

// ---------------- kernel 4: lamc[b][kc][v] ----------------
__global__ void k_lamc(float* __restrict__ ws) {
  const int b = blockIdx.x >> 4, kc = blockIdx.x & 15;
  const int v = threadIdx.x & 31, chunk = threadIdx.x >> 5;
  const float* st = ws + O_ST;
  const float sc = st[128 + v], bi = st[160 + v];
  float acc = 0.f;
  const int mbeg = chunk * 288;
  for (int m = mbeg; m < mbeg + 288; ++m) {
    float ek = __expf(ws[O_K + (size_t)(b * NNPOS + m) * 16 + kc]);
    float vn = ws[O_V + (size_t)(b * NNPOS + m) * 32 + v] * sc + bi;
    acc += ek * vn;
  }
  __shared__ float red[8][32];
  red[chunk][v] = acc;
  __syncthreads();
  if (chunk == 0) {
    float s = 0.f;
#pragma unroll
    for (int q = 0; q < 8; ++q) s += red[q][v];
    ws[O_LC + (size_t)(b * 16 + kc) * 32 + v] = s * st[192 + b * 16 + kc];
  }
}

// ---------------- kernel 5: lamp GEMM + fused Y epilogue (v2) ----------------
__global__ __launch_bounds__(256, 2) void k_lamp(float* __restrict__ ws,
                                                 float* __restrict__ out) {
  __shared__ __align__(16) char smem[33792];
  bf16x8* Bs16 = (bf16x8*)smem;                  // 512 x 16B units (8 KB)
  u32* Sw = (u32*)(smem + 8192);                 // S[16][50] bf16 = 400 words
  float* Cs = (float*)smem;                      // epilogue [64][132]

  const int t = threadIdx.x;
  const int bx = blockIdx.x;
  const int ni = bx / 6;
  const int sset = bx - ni * 6;
  const int s0 = (sset < 3) ? sset * 16 : (sset - 3) * 16 + 1;
  const int chalf = blockIdx.y;
  const int colbase = chalf * 128;
  const int wave = t >> 6, lane = t & 63;
  const int wrow = wave >> 1, wcol = wave & 1;
  const int lr = lane & 15, quad = lane >> 4;

  const __bf16* vp = (const __bf16*)(ws + O_VP);
  const unsigned short* rp = (const unsigned short*)(ws + O_RT);

  const int ia0 = t;
  const int kcA0 = ia0 / 24, wpA0 = ia0 - kcA0 * 24;
  const int ia1 = t + 256;
  const int kcA1 = ia1 / 24, wpA1 = ia1 - kcA1 * 24;
  const bool hasA1 = (ia1 < 384);

  const int colB0 = t >> 2, pB0 = ((t & 3) - ((t >> 3) & 3)) & 3;
  const int ub1 = t + 256;
  const int colB1 = ub1 >> 2, pB1 = ((ub1 & 3) - ((ub1 >> 3) & 3)) & 3;
  const __bf16* gB0 = vp + (size_t)(colbase + colB0) * 3072 + pB0 * 8;
  const __bf16* gB1 = vp + (size_t)(colbase + colB1) * 3072 + pB1 * 8;

  f32x4 acc[4][4];
  {
    f32x4 zz = {0.f, 0.f, 0.f, 0.f};
#pragma unroll
    for (int i = 0; i < 4; ++i)
#pragma unroll
      for (int j = 0; j < 4; ++j) acc[i][j] = zz;
  }

  u32 sa0 = 0, sa1 = 0;
  bf16x8 vb0, vb1;

  {
    const int P0 = 96 * (47 - ni) - s0 + 33;
    long b0 = (long)kcA0 * 9216 + P0 + 2 * wpA0;
    if (P0 & 1) sa0 = (u32)rp[b0] | ((u32)rp[b0 + 1] << 16);
    else        sa0 = *(const u32*)(rp + b0);
    if (hasA1) {
      long b1 = (long)kcA1 * 9216 + P0 + 2 * wpA1;
      if (P0 & 1) sa1 = (u32)rp[b1] | ((u32)rp[b1 + 1] << 16);
      else        sa1 = *(const u32*)(rp + b1);
    }
    vb0 = *(const bf16x8*)(gB0);
    vb1 = *(const bf16x8*)(gB1);
  }

  for (int ks = 0; ks < NK; ++ks) {
    __syncthreads();
    Sw[kcA0 * 25 + wpA0] = sa0;
    if (hasA1) Sw[kcA1 * 25 + wpA1] = sa1;
    Bs16[t] = vb0;
    Bs16[t + 256] = vb1;
    __syncthreads();

    if (ks < NK - 1) {
      const int ksn = ks + 1;
      const int mi = ksn >> 1, mj0 = (ksn & 1) << 5;
      const int P0 = 96 * (mi - ni + 47) + mj0 - s0 + 33;
      const int k0 = ksn * 32;
      long b0 = (long)kcA0 * 9216 + P0 + 2 * wpA0;
      if (P0 & 1) sa0 = (u32)rp[b0] | ((u32)rp[b0 + 1] << 16);
      else        sa0 = *(const u32*)(rp + b0);
      if (hasA1) {
        long b1 = (long)kcA1 * 9216 + P0 + 2 * wpA1;
        if (P0 & 1) sa1 = (u32)rp[b1] | ((u32)rp[b1 + 1] << 16);
        else        sa1 = *(const u32*)(rp + b1);
      }
      vb0 = *(const bf16x8*)(gB0 + k0);
      vb1 = *(const bf16x8*)(gB1 + k0);
    }

    bf16x8 af[4], bfr[4];
#pragma unroll
    for (int rt = 0; rt < 4; ++rt) {
      int nl = wrow * 4 + rt;
      int wb = lr * 25 + (7 - nl) + quad * 4;
      u32x4 dd = { Sw[wb], Sw[wb + 1], Sw[wb + 2], Sw[wb + 3] };
      af[rt] = __builtin_bit_cast(bf16x8, dd);
    }
#pragma unroll
    for (int ct = 0; ct < 4; ++ct) {
      int col = wcol * 64 + ct * 16 + lr;
      int u = col * 4 + ((quad + (col >> 1)) & 3);
      bfr[ct] = Bs16[u];
    }
#pragma unroll
    for (int rt = 0; rt < 4; ++rt)
#pragma unroll
      for (int ct = 0; ct < 4; ++ct)
        acc[rt][ct] = __builtin_amdgcn_mfma_f32_16x16x32_bf16(af[rt], bfr[ct], acc[rt][ct], 0, 0, 0);
  }

  const float* lamc = ws + O_LC;
  const float* Qp = ws + O_QP;
  float* CR = ws + O_CR;
  const int s = t >> 5, vv = t & 31;

  for (int h = 0; h < 2; ++h) {
    __syncthreads();
    if (wrow == h) {
#pragma unroll
      for (int rt = 0; rt < 4; ++rt) {
#pragma unroll
        for (int ct = 0; ct < 4; ++ct) {
          int col = wcol * 64 + ct * 16 + lr;
          int bb = chalf * 4 + (col >> 5);
          int vl = col & 31;
#pragma unroll
          for (int reg = 0; reg < 4; ++reg) {
            int row = rt * 16 + quad * 4 + reg;
            int kc = row & 15;
            Cs[row * 132 + col] = acc[rt][ct][reg] + lamc[(bb * 16 + kc) * 32 + vl];
          }
        }
      }
    }
    __syncthreads();
#pragma unroll
    for (int i = 0; i < 16; ++i) {
      int combo = s * 16 + i;
      int hp = combo & 7, bl = (combo >> 3) & 3, nr = combo >> 5;
      int n = ni * 48 + s0 + 2 * (h * 4 + nr);
      int bb = chalf * 4 + bl;
      const float* qrow = Qp + ((size_t)(n * 8 + bb) * 8 + hp) * 16;
      const float* crow = Cs + (nr * 16) * 132 + bl * 32 + vv;
      float y = 0.f;
#pragma unroll
      for (int kc = 0; kc < 16; ++kc) y += qrow[kc] * crow[kc * 132];
      float* dst = (hp < 4) ? out : CR;
      dst[(size_t)(bb * NNPOS + n) * 128 + (hp & 3) * 32 + vv] = y;
    }
  }
}

// ---------------- kernel: motion = CR @ WfT - cor @ Wg^T + b2 ----------------
__global__ void k_motion(const float* __restrict__ cor, float* __restrict__ ws,
                         float* __restrict__ out) {
  __shared__ float cr[16][128];
  __shared__ float cc[16][2];
  const int t = threadIdx.x;
  const int r0 = blockIdx.x * 16;
  for (int i = t; i < 2048; i += 256) cr[i >> 7][i & 127] = ws[O_CR + (size_t)r0 * 128 + i];
  if (t < 32) cc[t >> 1][t & 1] = cor[r0 * 2 + t];
  __syncthreads();
  const int o2 = t & 127, rg = t >> 7;
  const float* wft = ws + O_WF;
  float wg0 = ws[O_WG + o2 * 2], wg1 = ws[O_WG + o2 * 2 + 1], b2 = ws[O_B2 + o2];
  float acc[8];
#pragma unroll
  for (int j = 0; j < 8; ++j) {
    int row = rg + 2 * j;
    acc[j] = b2 - cc[row][0] * wg0 - cc[row][1] * wg1;
  }
  for (int c = 0; c < 128; ++c) {
    float w = wft[c * 128 + o2];
#pragma unroll
    for (int j = 0; j < 8; ++j) acc[j] += cr[rg + 2 * j][c] * w;
  }
#pragma unroll
  for (int j = 0; j < 8; ++j)
    out[2359296ul + (size_t)(r0 + rg + 2 * j) * 128 + o2] = acc[j];
}

// ---------------- launcher ----------------
extern "C" void kernel_launch(void* const* d_in, const int* in_sizes, int n_in,
                              void* d_out, int out_size, void* d_ws, size_t ws_size,
                              hipStream_t stream) {
  const float* x   = (const float*)d_in[0];
  const float* cor = (const float*)d_in[1];
  const float* Wq  = (const float*)d_in[2];
  const float* Wk  = (const float*)d_in[3];
  const float* Wv  = (const float*)d_in[4];
  const float* Wce = (const float*)d_in[5];
  const float* bce = (const float*)d_in[6];
  const float* Wcc = (const float*)d_in[7];
  const float* Wmp = (const float*)d_in[8];
  const float* bmp = (const float*)d_in[9];
  const float* gq  = (const float*)d_in[10];
  const float* bq  = (const float*)d_in[11];
  const float* gv  = (const float*)d_in[12];
  const float* bv  = (const float*)d_in[13];
  const float* rel = (const float*)d_in[14];
  float* out = (float*)d_out;
  float* ws  = (float*)d_ws;

  k_fold  <<<64, 256, 0, stream>>>(Wcc, Wce, Wmp, bmp, bce, Wq, Wk, Wv, ws);
  k_qkv   <<<288, 256, 0, stream>>>(x, ws);
  k_rt    <<<565, 256, 0, stream>>>(rel, ws);
  k_zero  <<<96, 256, 0, stream>>>(ws);
  k_stats <<<224, 256, 0, stream>>>(gq, bq, gv, bv, ws);
  k_prep  <<<2304, 256, 0, stream>>>(cor, Wce, bce, ws);
  k_lamc  <<<128, 256, 0, stream>>>(ws);
  k_lamp  <<<dim3(288, 2), 256, 0, stream>>>(ws, out);
  k_motion<<<1152, 256, 0, stream>>>(cor, ws, out);
}

// Round 4
// 261.150 us; speedup vs baseline: 1.8834x; 1.0250x over previous
//
#include <hip/hip_runtime.h>
#include <math.h>

// ---------------- constants ----------------
#define NNPOS 2304            // 48*48
#define ROWS  18432           // 8 * 2304
#define NK    96              // K-steps: 48 mi-blocks x 2 halves of padded-64

// workspace layout (float offsets)
#define O_Q   0ul             // q_raw [row][64]
#define O_K   1179648ul       // k_raw [row][16]
#define O_V   1474560ul       // v_raw [row][32]
#define O_ST  2064384ul       // scale_q[64] bias_q[64] scale_v[32] bias_v[32] denomInv[128]
#define O_VP  2064704ul       // Vp_g bf16 [256][3072] padded (393216 float slots)
#define O_QP  2457920ul       // Qp fp32 [n][b][8][16]
#define O_CE  4817216ul       // cor_embed_ [row][64] (unused now, kept)
#define O_LC  5996864ul       // lamc raw sums [b][16][32]
#define O_CR  6000960ul       // cor_reverse_ bf16 [row][128] (1.18M float slots used)
#define O_RT  8360256ul       // R_T bf16 [16][9216]  (73728 float slots)
#define O_WG  8450368ul       // Wg fp32 [o2][2] = Wmp@Wce       (256)
#define O_B2  8450624ul       // b2 fp32 [o2] = bmp - Wmp@bce    (128)
#define O_WB  8450752ul       // Wb bf16 [112][128]  (7168 float slots)
#define O_PT  8457920ul       // part_q [64][128]
#define O_PV  8466112ul       // part_v [32][64]
#define O_PE  8468160ul       // part_e [8][8][16]
#define O_WFB 8469184ul       // Wf bf16 [128 o2][128 c] (8192 float slots)

typedef __bf16 bf16x8 __attribute__((ext_vector_type(8)));
typedef float  f32x4  __attribute__((ext_vector_type(4)));
typedef unsigned int u32;
typedef u32 u32x4 __attribute__((ext_vector_type(4)));

// ---------------- kernel: fold motion weights + convert qkv weights to bf16 ----------------
__global__ void k_fold(const float* __restrict__ Wcc, const float* __restrict__ Wce,
                       const float* __restrict__ Wmp, const float* __restrict__ bmp,
                       const float* __restrict__ bce, const float* __restrict__ Wq,
                       const float* __restrict__ Wk, const float* __restrict__ Wv,
                       float* __restrict__ ws) {
  const int t = threadIdx.x;
  const int g = blockIdx.x * 256 + t;
  const int o2 = g >> 7, c = g & 127;
  float acc = 0.f;
#pragma unroll 8
  for (int o = 0; o < 64; ++o) acc += Wmp[o2 * 64 + o] * Wcc[o * 128 + c];
  ((__bf16*)(ws + O_WFB))[o2 * 128 + c] = (__bf16)acc;
  if (blockIdx.x == 0 && t < 128) {
    float a0 = 0.f, a1 = 0.f, ab = 0.f;
#pragma unroll 8
    for (int o = 0; o < 64; ++o) {
      float w = Wmp[t * 64 + o];
      a0 += w * Wce[o * 2]; a1 += w * Wce[o * 2 + 1]; ab += w * bce[o];
    }
    ws[O_WG + t * 2] = a0; ws[O_WG + t * 2 + 1] = a1; ws[O_B2 + t] = bmp[t] - ab;
  }
  // Wb bf16 [112][128] = concat(Wq, Wk, Wv)
  __bf16* wbp = (__bf16*)(ws + O_WB);
  if (g < 14336) {
    float w;
    if (g < 8192) w = Wq[g];
    else if (g < 10240) w = Wk[g - 8192];
    else w = Wv[g - 10240];
    wbp[g] = (__bf16)w;
  }
}

// ---------------- kernel 1: q,k,v via MFMA ----------------
__global__ __launch_bounds__(256) void k_qkv(const float* __restrict__ x,
                                             float* __restrict__ ws) {
  const int t = threadIdx.x;
  const int wave = t >> 6, lane = t & 63;
  const int lr = lane & 15, quad = lane >> 4;
  const int r0 = blockIdx.x * 64 + wave * 16;
  const int b = r0 / NNPOS;
  const int n0 = r0 - b * NNPOS;
  const size_t outbase = (size_t)(((b + 4) & 7)) * NNPOS + n0;

  const __bf16* wb = (const __bf16*)(ws + O_WB);
  const float* xrow = x + (size_t)(r0 + lr) * 128;

  f32x4 acc[7];
#pragma unroll
  for (int i = 0; i < 7; ++i) acc[i] = (f32x4){0.f, 0.f, 0.f, 0.f};

#pragma unroll
  for (int ks = 0; ks < 4; ++ks) {
    const float* ap = xrow + ks * 32 + quad * 8;
    float4 a0 = *(const float4*)(ap);
    float4 a1 = *(const float4*)(ap + 4);
    bf16x8 af;
    af[0] = (__bf16)a0.x; af[1] = (__bf16)a0.y; af[2] = (__bf16)a0.z; af[3] = (__bf16)a0.w;
    af[4] = (__bf16)a1.x; af[5] = (__bf16)a1.y; af[6] = (__bf16)a1.z; af[7] = (__bf16)a1.w;
#pragma unroll
    for (int ct = 0; ct < 7; ++ct) {
      bf16x8 bfrag = *(const bf16x8*)(wb + (ct * 16 + lr) * 128 + ks * 32 + quad * 8);
      acc[ct] = __builtin_amdgcn_mfma_f32_16x16x32_bf16(af, bfrag, acc[ct], 0, 0, 0);
    }
  }

#pragma unroll
  for (int ct = 0; ct < 7; ++ct) {
#pragma unroll
    for (int reg = 0; reg < 4; ++reg) {
      int m = quad * 4 + reg;
      int oc = ct * 16 + lr;
      float vvv = acc[ct][reg];
      if (ct < 4)      ws[O_Q + (size_t)(r0 + m) * 64 + oc] = vvv;
      else if (ct < 5) ws[O_K + (outbase + m) * 16 + (oc - 64)] = vvv;
      else             ws[O_V + (outbase + m) * 32 + (oc - 80)] = vvv;
    }
  }
}

// ---------------- kernel: transpose rel_pos_emb -> R_T bf16 [16][96*96] ----------------
__global__ void k_rt(const float* __restrict__ rel, float* __restrict__ ws) {
  __bf16* rt = (__bf16*)(ws + O_RT);
  int i = blockIdx.x * 256 + threadIdx.x;
  if (i < 144400) {
    int kc = i & 15, rr = i >> 4;
    int ri = rr / 95, rj = rr - ri * 95;
    rt[(size_t)kc * 9216 + ri * 96 + rj] = (__bf16)rel[i];
  }
}

// ---------------- kernel: zero Vp pad + lamc accumulator ----------------
__global__ void k_zero(float* __restrict__ ws) {
  __bf16* vp = (__bf16*)(ws + O_VP);
  int i = blockIdx.x * 256 + threadIdx.x;   // < 24576
  if (i < 4096) ws[O_LC + i] = 0.f;
  int bv = i / 96, rem = i - bv * 96;
  int mi = rem >> 1, h8 = rem & 1;
  uint4 z; z.x = 0; z.y = 0; z.z = 0; z.w = 0;
  *(uint4*)(vp + (size_t)bv * 3072 + mi * 64 + 48 + h8 * 8) = z;
}

// ---------------- kernel 2a: stats partials (coalesced) ----------------
__global__ void k_stats1(float* __restrict__ ws) {
  const int t = threadIdx.x, blk = blockIdx.x;
  __shared__ float sh[512];
  if (blk < 64) {            // q rows slice: 288 rows, 64 ch
    const int ch = t & 63, rsub = t >> 6;
    const float* src = ws + O_Q;
    const int r0 = blk * 288;
    float s = 0.f, s2 = 0.f;
#pragma unroll 4
    for (int i = 0; i < 72; ++i) {
      float v = src[(size_t)(r0 + rsub + i * 4) * 64 + ch];
      s += v; s2 += v * v;
    }
    sh[t] = s; sh[256 + t] = s2;
    __syncthreads();
    if (t < 64) {
      float S = sh[t] + sh[t + 64] + sh[t + 128] + sh[t + 192];
      float S2 = sh[256 + t] + sh[256 + t + 64] + sh[256 + t + 128] + sh[256 + t + 192];
      ws[O_PT + blk * 128 + t * 2] = S; ws[O_PT + blk * 128 + t * 2 + 1] = S2;
    }
  } else if (blk < 96) {     // v rows slice: 576 rows, 32 ch
    const int j = blk - 64;
    const int ch = t & 31, rsub = t >> 5;
    const float* src = ws + O_V;
    const int r0 = j * 576;
    float s = 0.f, s2 = 0.f;
#pragma unroll 4
    for (int i = 0; i < 72; ++i) {
      float v = src[(size_t)(r0 + rsub + i * 8) * 32 + ch];
      s += v; s2 += v * v;
    }
    sh[t] = s; sh[256 + t] = s2;
    __syncthreads();
    if (t < 32) {
      float S = 0.f, S2 = 0.f;
#pragma unroll
      for (int k = 0; k < 8; ++k) { S += sh[t + k * 32]; S2 += sh[256 + t + k * 32]; }
      ws[O_PV + j * 64 + t * 2] = S; ws[O_PV + j * 64 + t * 2 + 1] = S2;
    }
  } else {                   // exp-K partial: b = idx>>3, slice = idx&7 (288 rows, 16 kc)
    const int idx = blk - 96;
    const int b = idx >> 3, sl = idx & 7;
    const int kc = t & 15, rsub = t >> 4;
    const int r0 = b * 2304 + sl * 288;
    float s = 0.f;
#pragma unroll 2
    for (int i = 0; i < 18; ++i)
      s += __expf(ws[O_K + (size_t)(r0 + rsub + i * 16) * 16 + kc]);
    sh[t] = s;
    __syncthreads();
    if (t < 16) {
      float S = 0.f;
#pragma unroll
      for (int k = 0; k < 16; ++k) S += sh[t + k * 16];
      ws[O_PE + b * 128 + sl * 16 + t] = S;
    }
  }
}

// ---------------- kernel 2b: finalize stats ----------------
__global__ void k_stats2(const float* __restrict__ gq, const float* __restrict__ bq,
                         const float* __restrict__ gv, const float* __restrict__ bv,
                         float* __restrict__ ws) {
  const int t = threadIdx.x;
  if (t < 64) {
    float S = 0.f, S2 = 0.f;
    for (int i = 0; i < 64; ++i) { S += ws[O_PT + i * 128 + t * 2]; S2 += ws[O_PT + i * 128 + t * 2 + 1]; }
    float mu = S / 18432.f, var = S2 / 18432.f - mu * mu;
    float sc = gq[t] * rsqrtf(var + 1e-5f);
    ws[O_ST + t] = sc; ws[O_ST + 64 + t] = bq[t] - mu * sc;
  } else if (t < 96) {
    int ch = t - 64;
    float S = 0.f, S2 = 0.f;
    for (int i = 0; i < 32; ++i) { S += ws[O_PV + i * 64 + ch * 2]; S2 += ws[O_PV + i * 64 + ch * 2 + 1]; }
    float mu = S / 18432.f, var = S2 / 18432.f - mu * mu;
    float sc = gv[ch] * rsqrtf(var + 1e-5f);
    ws[O_ST + 128 + ch] = sc; ws[O_ST + 160 + ch] = bv[ch] - mu * sc;
  } else if (t < 224) {
    int idx = t - 96; int b = idx >> 4, kc = idx & 15;
    float S = 0.f;
#pragma unroll
    for (int sl = 0; sl < 8; ++sl) S += ws[O_PE + b * 128 + sl * 16 + kc];
    ws[O_ST + 192 + idx] = 1.f / S;
  }
}

// ---------------- kernel 3: build Vp_g (bf16, padded), Qp ----------------
__global__ void k_prep(const float* __restrict__ cor, const float* __restrict__ Wce,
                       const float* __restrict__ bce, float* __restrict__ ws) {
  const int t = threadIdx.x;
  const int rl = t >> 5, j = t & 31;
  const int rid = blockIdx.x * 8 + rl;
  const int b = rid / NNPOS, n = rid - b * NNPOS;
  const float* st = ws + O_ST;
  __bf16* vp = (__bf16*)(ws + O_VP);
  float vvn = ws[O_V + (size_t)rid * 32 + j] * st[128 + j] + st[160 + j];
  vp[(size_t)(b * 32 + j) * 3072 + (n / 48) * 64 + (n % 48)] = (__bf16)vvn;
  float c0 = cor[rid * 2], c1 = cor[rid * 2 + 1];
#pragma unroll
  for (int ch = j; ch < 64; ch += 32) {
    float qn = ws[O_Q + (size_t)rid * 64 + ch] * st[ch] + st[64 + ch];
    ws[O_QP + (size_t)(n * 8 + b) * 128 + ch] = qn;
    float ce = c0 * Wce[ch * 2] + c1 * Wce[ch * 2 + 1] + bce[ch];
    ws[O_QP + (size_t)(n * 8 + b) * 128 + 64 + ch] = ce;
  }
}

// ---------------- kernel 4: lamc raw sums (split-m, LDS-staged, atomic) ----------------
__global__ void k_lamc(float* __restrict__ ws) {
  const int b = blockIdx.x / 9, sl = blockIdx.x - b * 9;
  const int t = threadIdx.x;
  __shared__ float eK[16][16];
  __shared__ float Vn[16][33];
  const float* st = ws + O_ST;
  const int kc = t & 15, vp_ = t >> 4;
  const int v0 = vp_ * 2, v1 = v0 + 1;
  float a0 = 0.f, a1 = 0.f;
  const int m0 = b * 2304 + sl * 256;
  const int jj = t & 31, rw = t >> 5;
  const float scj = st[128 + jj], bij = st[160 + jj];
  for (int ch = 0; ch < 16; ++ch) {
    const int mbase = m0 + ch * 16;
    eK[t >> 4][t & 15] = __expf(ws[O_K + (size_t)(mbase + (t >> 4)) * 16 + (t & 15)]);
    Vn[rw][jj]     = ws[O_V + (size_t)(mbase + rw) * 32 + jj] * scj + bij;
    Vn[rw + 8][jj] = ws[O_V + (size_t)(mbase + rw + 8) * 32 + jj] * scj + bij;
    __syncthreads();
#pragma unroll
    for (int m = 0; m < 16; ++m) {
      float e = eK[m][kc];
      a0 += e * Vn[m][v0];
      a1 += e * Vn[m][v1];
    }
    __syncthreads();
  }
  atomicAdd(&ws[O_LC + (size_t)(b * 16 + kc) * 32 + v0], a0);
  atomicAdd(&ws[O_LC + (size_t)(b * 16 + kc) * 32 + v1], a1);
}

// ---------------- kernel 5: lamp GEMM + fused Y epilogue (depth-2 prefetch) ----------------
__global__ __launch_bounds__(256, 2) void k_lamp(float* __restrict__ ws,
                                                 float* __restrict__ out) {
  __shared__ __align__(16) char smem[33792];
  bf16x8* Bs16 = (bf16x8*)smem;                  // 512 x 16B units (8 KB)
  u32* Sw = (u32*)(smem + 8192);                 // S[16][50] bf16 = 400 words
  float* Cs = (float*)smem;                      // epilogue [64][132]

  const int t = threadIdx.x;
  const int bx = blockIdx.x;
  const int ni = bx / 6;
  const int sset = bx - ni * 6;
  const int s0 = (sset < 3) ? sset * 16 : (sset - 3) * 16 + 1;
  const int chalf = blockIdx.y;
  const int colbase = chalf * 128;
  const int wave = t >> 6, lane = t & 63;
  const int wrow = wave >> 1, wcol = wave & 1;
  const int lr = lane & 15, quad = lane >> 4;

  const __bf16* vp = (const __bf16*)(ws + O_VP);
  const unsigned short* rp = (const unsigned short*)(ws + O_RT);

  const int ia0 = t;
  const int kcA0 = ia0 / 24, wpA0 = ia0 - kcA0 * 24;
  const int ia1 = t + 256;
  const int kcA1 = ia1 / 24, wpA1 = ia1 - kcA1 * 24;
  const bool hasA1 = (ia1 < 384);

  const int colB0 = t >> 2, pB0 = ((t & 3) - ((t >> 3) & 3)) & 3;
  const int ub1 = t + 256;
  const int colB1 = ub1 >> 2, pB1 = ((ub1 & 3) - ((ub1 >> 3) & 3)) & 3;
  const __bf16* gB0 = vp + (size_t)(colbase + colB0) * 3072 + pB0 * 8;
  const __bf16* gB1 = vp + (size_t)(colbase + colB1) * 3072 + pB1 * 8;

  f32x4 acc[4][4];
  {
    f32x4 zz = {0.f, 0.f, 0.f, 0.f};
#pragma unroll
    for (int i = 0; i < 4; ++i)
#pragma unroll
      for (int j = 0; j < 4; ++j) acc[i][j] = zz;
  }

  // two prefetch buffers
  u32 sa[2] = {0, 0}, sb[2] = {0, 0};
  bf16x8 vA[2], vB[2];

  auto loadStep = [&](int ksn, u32& sA_, u32& sB_, bf16x8& v0_, bf16x8& v1_) {
    const int mi = ksn >> 1, mj0 = (ksn & 1) << 5;
    const int P0 = 96 * (mi - ni + 47) + mj0 - s0 + 33;
    const int k0 = ksn * 32;
    long b0 = (long)kcA0 * 9216 + P0 + 2 * wpA0;
    if (P0 & 1) sA_ = (u32)rp[b0] | ((u32)rp[b0 + 1] << 16);
    else        sA_ = *(const u32*)(rp + b0);
    if (hasA1) {
      long b1 = (long)kcA1 * 9216 + P0 + 2 * wpA1;
      if (P0 & 1) sB_ = (u32)rp[b1] | ((u32)rp[b1 + 1] << 16);
      else        sB_ = *(const u32*)(rp + b1);
    }
    v0_ = *(const bf16x8*)(gB0 + k0);
    v1_ = *(const bf16x8*)(gB1 + k0);
  };

  loadStep(0, sa[0], sb[0], vA[0], vB[0]);
  loadStep(1, sa[1], sb[1], vA[1], vB[1]);

  auto step = [&](int ks, u32& sA_, u32& sB_, bf16x8& v0_, bf16x8& v1_) {
    __syncthreads();
    Sw[kcA0 * 25 + wpA0] = sA_;
    if (hasA1) Sw[kcA1 * 25 + wpA1] = sB_;
    Bs16[t] = v0_;
    Bs16[t + 256] = v1_;
    __syncthreads();
    if (ks + 2 < NK) loadStep(ks + 2, sA_, sB_, v0_, v1_);

    bf16x8 af[4], bfr[4];
#pragma unroll
    for (int rt = 0; rt < 4; ++rt) {
      int nl = wrow * 4 + rt;
      int wb = lr * 25 + (7 - nl) + quad * 4;
      u32x4 dd = { Sw[wb], Sw[wb + 1], Sw[wb + 2], Sw[wb + 3] };
      af[rt] = __builtin_bit_cast(bf16x8, dd);
    }
#pragma unroll
    for (int ct = 0; ct < 4; ++ct) {
      int col = wcol * 64 + ct * 16 + lr;
      int u = col * 4 + ((quad + (col >> 1)) & 3);
      bfr[ct] = Bs16[u];
    }
#pragma unroll
    for (int rt = 0; rt < 4; ++rt)
#pragma unroll
      for (int ct = 0; ct < 4; ++ct)
        acc[rt][ct] = __builtin_amdgcn_mfma_f32_16x16x32_bf16(af[rt], bfr[ct], acc[rt][ct], 0, 0, 0);
  };

  for (int ks2 = 0; ks2 < NK; ks2 += 2) {
    step(ks2,     sa[0], sb[0], vA[0], vB[0]);
    step(ks2 + 1, sa[1], sb[1], vA[1], vB[1]);
  }

  const float* lamc = ws + O_LC;
  const float* Qp = ws + O_QP;
  __bf16* CRb = (__bf16*)(ws + O_CR);
  const int s = t >> 5, vv = t & 31;

  for (int h = 0; h < 2; ++h) {
    __syncthreads();
    if (wrow == h) {
#pragma unroll
      for (int rt = 0; rt < 4; ++rt) {
#pragma unroll
        for (int ct = 0; ct < 4; ++ct) {
          int col = wcol * 64 + ct * 16 + lr;
          int bb = chalf * 4 + (col >> 5);
          int vl = col & 31;
#pragma unroll
          for (int reg = 0; reg < 4; ++reg) {
            int row = rt * 16 + quad * 4 + reg;
            int kc = row & 15;
            float dinv = ws[O_ST + 192 + bb * 16 + kc];
            Cs[row * 132 + col] = acc[rt][ct][reg] + lamc[(bb * 16 + kc) * 32 + vl] * dinv;
          }
        }
      }
    }
    __syncthreads();
#pragma unroll
    for (int i = 0; i < 16; ++i) {
      int combo = s * 16 + i;
      int hp = combo & 7, bl = (combo >> 3) & 3, nr = combo >> 5;
      int n = ni * 48 + s0 + 2 * (h * 4 + nr);
      int bb = chalf * 4 + bl;
      const float* qrow = Qp + ((size_t)(n * 8 + bb) * 8 + hp) * 16;
      const float* crow = Cs + (nr * 16) * 132 + bl * 32 + vv;
      float y = 0.f;
#pragma unroll
      for (int kc = 0; kc < 16; ++kc) y += qrow[kc] * crow[kc * 132];
      size_t idx = (size_t)(bb * NNPOS + n) * 128 + (hp & 3) * 32 + vv;
      if (hp < 4) out[idx] = y;
      else        CRb[idx] = (__bf16)y;
    }
  }
}

// ---------------- kernel: motion via MFMA  (CRb @ Wfb^T + affine(cor)) ----------------
__global__ __launch_bounds__(256) void k_motion(const float* __restrict__ cor,
                                                float* __restrict__ ws,
                                                float* __restrict__ out) {
  const int t = threadIdx.x;
  const int wave = t >> 6, lane = t & 63;
  const int lr = lane & 15, quad = lane >> 4;
  const int r0 = blockIdx.x * 64 + wave * 16;
  const __bf16* crb = (const __bf16*)(ws + O_CR);
  const __bf16* wfb = (const __bf16*)(ws + O_WFB);

  f32x4 acc[8];
#pragma unroll
  for (int i = 0; i < 8; ++i) acc[i] = (f32x4){0.f, 0.f, 0.f, 0.f};

#pragma unroll
  for (int ks = 0; ks < 4; ++ks) {
    bf16x8 af = *(const bf16x8*)(crb + (size_t)(r0 + lr) * 128 + ks * 32 + quad * 8);
#pragma unroll
    for (int ct = 0; ct < 8; ++ct) {
      bf16x8 bfrag = *(const bf16x8*)(wfb + (ct * 16 + lr) * 128 + ks * 32 + quad * 8);
      acc[ct] = __builtin_amdgcn_mfma_f32_16x16x32_bf16(af, bfrag, acc[ct], 0, 0, 0);
    }
  }

#pragma unroll
  for (int reg = 0; reg < 4; ++reg) {
    int row = r0 + quad * 4 + reg;
    float c0 = cor[row * 2], c1 = cor[row * 2 + 1];
#pragma unroll
    for (int ct = 0; ct < 8; ++ct) {
      int o2 = ct * 16 + lr;
      float y = acc[ct][reg] + ws[O_B2 + o2] - c0 * ws[O_WG + o2 * 2] - c1 * ws[O_WG + o2 * 2 + 1];
      out[2359296ul + (size_t)row * 128 + o2] = y;
    }
  }
}

// ---------------- launcher ----------------
extern "C" void kernel_launch(void* const* d_in, const int* in_sizes, int n_in,
                              void* d_out, int out_size, void* d_ws, size_t ws_size,
                              hipStream_t stream) {
  const float* x   = (const float*)d_in[0];
  const float* cor = (const float*)d_in[1];
  const float* Wq  = (const float*)d_in[2];
  const float* Wk  = (const float*)d_in[3];
  const float* Wv  = (const float*)d_in[4];
  const float* Wce = (const float*)d_in[5];
  const float* bce = (const float*)d_in[6];
  const float* Wcc = (const float*)d_in[7];
  const float* Wmp = (const float*)d_in[8];
  const float* bmp = (const float*)d_in[9];
  const float* gq  = (const float*)d_in[10];
  const float* bq  = (const float*)d_in[11];
  const float* gv  = (const float*)d_in[12];
  const float* bv  = (const float*)d_in[13];
  const float* rel = (const float*)d_in[14];
  float* out = (float*)d_out;
  float* ws  = (float*)d_ws;

  k_fold  <<<64, 256, 0, stream>>>(Wcc, Wce, Wmp, bmp, bce, Wq, Wk, Wv, ws);
  k_qkv   <<<288, 256, 0, stream>>>(x, ws);
  k_rt    <<<565, 256, 0, stream>>>(rel, ws);
  k_zero  <<<96, 256, 0, stream>>>(ws);
  k_stats1<<<160, 256, 0, stream>>>(ws);
  k_stats2<<<1, 256, 0, stream>>>(gq, bq, gv, bv, ws);
  k_lamc  <<<72, 256, 0, stream>>>(ws);
  k_prep  <<<2304, 256, 0, stream>>>(cor, Wce, bce, ws);
  k_lamp  <<<dim3(288, 2), 256, 0, stream>>>(ws, out);
  k_motion<<<288, 256, 0, stream>>>(cor, ws, out);
}